// Round 1
// baseline (71467.633 us; speedup 1.0000x reference)
//
#include <hip/hip_runtime.h>
#include <math.h>

#define BB 64
#define TT 600
#define KMIX 10
#define UU 64
#define CDIM 54
#define HH 512
#define OUTD 121
#define SROW 1088
// state-row slots
#define SX0 0      // x(t)   len 3
#define SX1 3      // x(t+1) len 3
#define SW  6      // w      len 54   -> [3:60) contiguous [x(t+1), w] for gates1
#define SH1 64     // h1     len 512
#define SH2 576    // h2     len 512
#define LDW1 60
#define LDW2 572

// ws layout in floats
enum : int {
  OFF_S0   = 0,
  OFF_S1   = 69632,           // 64*1088
  OFF_C1   = 139264,
  OFF_C2   = 172032,
  OFF_KAP  = 204800,          // 64*10
  OFF_LOSS = 205440,          // 64
  OFF_OUTB = 205504,          // 64*121
  OFF_W1P  = 213248,          // 2048*60
  OFF_W2P  = 336128,          // 2048*572
  WS_FLOATS = 1507584
};

__device__ __forceinline__ float sigm(float v) { return 1.0f / (1.0f + expf(-v)); }

__global__ __launch_bounds__(256) void k_init0(float* ws)
{
  int i = blockIdx.x * 256 + threadIdx.x;
  int stride = gridDim.x * 256;
  for (; i < OFF_W1P; i += stride) ws[i] = 0.0f;
}

__global__ __launch_bounds__(256) void k_init1(float* ws, const float* __restrict__ x,
                                               const float* __restrict__ Wih1,
                                               const float* __restrict__ Wih2)
{
  const int N1 = 2048 * LDW1;
  const int N2 = 2048 * LDW2;
  int i = blockIdx.x * 256 + threadIdx.x;
  int stride = gridDim.x * 256;
  for (; i < N1 + N2 + 192; i += stride) {
    if (i < N1) {
      int c = i / LDW1, k = i - c * LDW1;
      ws[OFF_W1P + i] = (k < 57) ? Wih1[c * 57 + k] : 0.0f;
    } else if (i < N1 + N2) {
      int j = i - N1;
      int c = j / LDW2, k = j - c * LDW2;
      float v = 0.0f;
      if (k < 512)      v = Wih2[c * 569 + 3 + k];        // h1 cols
      else if (k < 515) v = Wih2[c * 569 + (k - 512)];    // x cols
      else if (k < 569) v = Wih2[c * 569 + k];            // w cols
      ws[OFF_W2P + j] = v;
    } else {
      int j = i - N1 - N2;
      int b = j / 3, k = j - b * 3;
      ws[OFF_S0 + b * SROW + SX1 + k] = x[(b * TT + 0) * 3 + k];  // x(0) for gates1(0)
    }
  }
}

// alpha: blocks 0..127 gates2(t); blocks 128..255 gates1(t+1) + proj(t-1)
__global__ __launch_bounds__(256) void k_alpha(int t,
    const float* __restrict__ Scur, float* __restrict__ Snxt,
    float* __restrict__ c1ws, float* __restrict__ c2ws,
    const float* __restrict__ w1p, const float* __restrict__ w2p,
    const float* __restrict__ whh1, const float* __restrict__ whh2,
    const float* __restrict__ bih1, const float* __restrict__ bhh1,
    const float* __restrict__ bih2, const float* __restrict__ bhh2,
    const float* __restrict__ Wo, const float* __restrict__ bo,
    float* __restrict__ outbuf)
{
  __shared__ float Alds[64 * 68];
  const int w = blockIdx.x;
  const int tid = threadIdx.x;
  const int b = tid >> 2, di = tid & 3;

  float acc0 = 0.f, acc1 = 0.f, acc2 = 0.f, acc3 = 0.f;
  int D = 0;

  auto vecseg = [&](int Sofs, const float* Wb, int ldw, int wcol) {
    for (int k0 = 0; k0 < 512; k0 += 64) {
      __syncthreads();
      int r = tid >> 4, c4 = (tid & 15) * 4;
      #pragma unroll
      for (int p = 0; p < 4; ++p) {
        float4 v = *reinterpret_cast<const float4*>(&Scur[(r + 16 * p) * SROW + Sofs + k0 + c4]);
        *reinterpret_cast<float4*>(&Alds[(r + 16 * p) * 68 + c4]) = v;
      }
      __syncthreads();
      const float* w0 = Wb + (0 * HH + D) * ldw + wcol + k0;
      const float* w1 = Wb + (1 * HH + D) * ldw + wcol + k0;
      const float* w2 = Wb + (2 * HH + D) * ldw + wcol + k0;
      const float* w3 = Wb + (3 * HH + D) * ldw + wcol + k0;
      const float* ar = &Alds[b * 68];
      #pragma unroll 8
      for (int kk = 0; kk < 64; kk += 4) {
        float4 a  = *reinterpret_cast<const float4*>(&ar[kk]);
        float4 q0 = *reinterpret_cast<const float4*>(&w0[kk]);
        float4 q1 = *reinterpret_cast<const float4*>(&w1[kk]);
        float4 q2 = *reinterpret_cast<const float4*>(&w2[kk]);
        float4 q3 = *reinterpret_cast<const float4*>(&w3[kk]);
        acc0 += a.x * q0.x + a.y * q0.y + a.z * q0.z + a.w * q0.w;
        acc1 += a.x * q1.x + a.y * q1.y + a.z * q1.z + a.w * q1.w;
        acc2 += a.x * q2.x + a.y * q2.y + a.z * q2.z + a.w * q2.w;
        acc3 += a.x * q3.x + a.y * q3.y + a.z * q3.z + a.w * q3.w;
      }
    }
  };

  auto scalseg = [&](int Sofs, int len, const float* Wb, int ldw, int wcol) {
    __syncthreads();
    for (int i = tid; i < 64 * 64; i += 256) {
      int r = i >> 6, c = i & 63;
      if (c < len) Alds[r * 68 + c] = Scur[r * SROW + Sofs + c];
    }
    __syncthreads();
    const float* w0 = Wb + (0 * HH + D) * ldw + wcol;
    const float* w1 = Wb + (1 * HH + D) * ldw + wcol;
    const float* w2 = Wb + (2 * HH + D) * ldw + wcol;
    const float* w3 = Wb + (3 * HH + D) * ldw + wcol;
    const float* ar = &Alds[b * 68];
    for (int k = 0; k < len; ++k) {
      float a = ar[k];
      acc0 += a * w0[k]; acc1 += a * w1[k]; acc2 += a * w2[k]; acc3 += a * w3[k];
    }
  };

  if (w < 128) {
    if (t < 0) return;
    D = 4 * w + di;
    vecseg(SH1, w2p, LDW2, 0);
    vecseg(SH2, whh2, HH, 0);
    scalseg(SX0, 3, w2p, LDW2, 512);
    scalseg(SW, 54, w2p, LDW2, 515);
    float ig = sigm(acc0 + bih2[D] + bhh2[D]);
    float fg = sigm(acc1 + bih2[HH + D] + bhh2[HH + D]);
    float gg = tanhf(acc2 + bih2[2 * HH + D] + bhh2[2 * HH + D]);
    float og = sigm(acc3 + bih2[3 * HH + D] + bhh2[3 * HH + D]);
    float c = c2ws[b * HH + D];
    c = fg * c + ig * gg;
    c2ws[b * HH + D] = c;
    Snxt[b * SROW + SH2 + D] = og * tanhf(c);
  } else {
    int w1b = w - 128;
    if (t <= 598) {
      D = 4 * w1b + di;
      scalseg(SX1, 57, w1p, LDW1, 0);     // [x(t+1), w(t)]
      vecseg(SH1, whh1, HH, 0);           // h1(t)
      float ig = sigm(acc0 + bih1[D] + bhh1[D]);
      float fg = sigm(acc1 + bih1[HH + D] + bhh1[HH + D]);
      float gg = tanhf(acc2 + bih1[2 * HH + D] + bhh1[2 * HH + D]);
      float og = sigm(acc3 + bih1[3 * HH + D] + bhh1[3 * HH + D]);
      float c = c1ws[b * HH + D];
      c = fg * c + ig * gg;
      c1ws[b * HH + D] = c;
      Snxt[b * SROW + SH1 + D] = og * tanhf(c);
    }
    if (t >= 1) {   // projection of h2(t-1): outputs(t-1) = h2 @ Wo^T + bo
      __syncthreads();
      int pb = w1b >> 1, half = w1b & 1;
      for (int i = tid; i < 512; i += 256) Alds[i] = Scur[pb * SROW + SH2 + i];
      __syncthreads();
      int to = tid >> 2, ks = tid & 3;
      int nout = half ? 60 : 61;
      int o = half * 61 + to;
      float a = 0.f;
      if (to < nout) {
        const float* wr = Wo + o * HH + ks * 128;
        const float* hr = &Alds[ks * 128];
        #pragma unroll 8
        for (int kk = 0; kk < 128; kk += 4) {
          float4 q = *reinterpret_cast<const float4*>(&wr[kk]);
          float4 h4 = *reinterpret_cast<const float4*>(&hr[kk]);
          a += q.x * h4.x + q.y * h4.y + q.z * h4.z + q.w * h4.w;
        }
      }
      a += __shfl_xor(a, 1);
      a += __shfl_xor(a, 2);
      if (ks == 0 && to < nout) outbuf[pb * OUTD + o] = a + bo[o];
    }
  }
}

__device__ __forceinline__ void mix_loss_block(const float* so, const float* __restrict__ y,
                                               int b, int tf, float* lossacc, int tid)
{
  if (tid >= 32) return;
  int m = tid;
  float y1 = y[(b * TT + tf) * 3 + 0];
  float y2 = y[(b * TT + tf) * 3 + 1];
  float ys = y[(b * TT + tf) * 3 + 2];
  float ph = (m < 20) ? so[1 + m] : -1e30f;
  float mx = ph;
  #pragma unroll
  for (int d = 16; d >= 1; d >>= 1) mx = fmaxf(mx, __shfl_xor(mx, d));
  float pe = (m < 20) ? expf(ph - mx) : 0.0f;
  float ps = pe;
  #pragma unroll
  for (int d = 16; d >= 1; d >>= 1) ps += __shfl_xor(ps, d);
  float contrib = 0.0f;
  if (m < 20) {
    float mu1 = so[21 + m], mu2 = so[41 + m];
    float s1 = expf(so[61 + m]), s2 = expf(so[81 + m]);
    float rh = tanhf(so[101 + m]);
    float d1 = (y1 - mu1) / s1, d2v = (y2 - mu2) / s2;
    float omr = 1.0f - rh * rh;
    float z = d1 * d1 + d2v * d2v - 2.0f * rh * d1 * d2v;
    float ga = expf(-z / (2.0f * omr)) / (6.28318530717958647692f * s1 * s2 * sqrtf(omr));
    contrib = (pe / ps) * ga;
  }
  float gs = contrib;
  #pragma unroll
  for (int d = 16; d >= 1; d >>= 1) gs += __shfl_xor(gs, d);
  if (m == 0) {
    float lg = -logf(gs + 1e-20f);
    float e = 1.0f / (1.0f + expf(so[0]));
    float lb = -logf((e + 1e-20f) * ys + (1.0f - e + 1e-20f) * (1.0f - ys));
    lossacc[b] += lg + lb;
  }
}

// beta: blocks 0..63 attention(t+1); blocks 64..127 loss finalize(t-1)
__global__ __launch_bounds__(256) void k_beta(int t,
    const float* __restrict__ x, const float* __restrict__ y, const float* __restrict__ cvec,
    const float* __restrict__ Wk, const float* __restrict__ bk,
    float* __restrict__ Snxt, float* __restrict__ kapws,
    const float* __restrict__ outbuf, float* __restrict__ lossacc)
{
  int blk = blockIdx.x, tid = threadIdx.x;
  if (blk < 64) {
    if (t > 598) return;
    int b = blk;
    __shared__ float sh1[512];
    __shared__ float skg[30], sal[10], sbe[10], ska[10], sphi[64];
    for (int i = tid; i < 512; i += 256) sh1[i] = Snxt[b * SROW + SH1 + i];
    __syncthreads();
    {
      int j = tid >> 3, ks = tid & 7;
      float a = 0.f;
      if (j < 30) {
        const float* wr = Wk + j * HH + ks * 64;
        const float* hr = &sh1[ks * 64];
        #pragma unroll 8
        for (int kk = 0; kk < 64; kk += 4) {
          float4 q = *reinterpret_cast<const float4*>(&wr[kk]);
          float4 h4 = *reinterpret_cast<const float4*>(&hr[kk]);
          a += q.x * h4.x + q.y * h4.y + q.z * h4.z + q.w * h4.w;
        }
      }
      a += __shfl_xor(a, 1); a += __shfl_xor(a, 2); a += __shfl_xor(a, 4);
      if (j < 30 && ks == 0) skg[j] = a + bk[j];
    }
    __syncthreads();
    if (tid < 10) {
      float al = expf(skg[tid]);
      float be = expf(skg[10 + tid]);
      float kp = kapws[b * 10 + tid] + expf(skg[20 + tid]);
      kapws[b * 10 + tid] = kp;
      sal[tid] = al; sbe[tid] = be; ska[tid] = kp;
    }
    __syncthreads();
    if (tid < 64) {
      float u = (float)tid, phv = 0.f;
      #pragma unroll
      for (int k = 0; k < 10; ++k) { float d = ska[k] - u; phv += sal[k] * expf(-sbe[k] * d * d); }
      sphi[tid] = phv;
    }
    __syncthreads();
    if (tid < CDIM) {
      float wv = 0.f;
      for (int u = 0; u < 64; ++u) wv += sphi[u] * cvec[(b * UU + u) * CDIM + tid];
      Snxt[b * SROW + SW + tid] = wv;
    }
    if (tid >= 64 && tid < 67)
      Snxt[b * SROW + SX0 + (tid - 64)] = x[(b * TT + (t + 1)) * 3 + (tid - 64)];
    if (tid >= 67 && tid < 70)
      Snxt[b * SROW + SX1 + (tid - 67)] = (t + 2 <= 599) ? x[(b * TT + (t + 2)) * 3 + (tid - 67)] : 0.0f;
  } else {
    if (t < 1) return;
    int b = blk - 64, tf = t - 1;
    __shared__ float so[OUTD];
    for (int i = tid; i < OUTD; i += 256) so[i] = outbuf[b * OUTD + i];
    __syncthreads();
    mix_loss_block(so, y, b, tf, lossacc, tid);
  }
}

// epilogue 1: projection + loss for t = 599 (h2(599) lives in S1)
__global__ __launch_bounds__(256) void k_ep1(const float* __restrict__ S1p,
    const float* __restrict__ Wo, const float* __restrict__ bo,
    const float* __restrict__ y, float* __restrict__ lossacc)
{
  int b = blockIdx.x, tid = threadIdx.x;
  __shared__ float sh2[512];
  __shared__ float so[OUTD];
  for (int i = tid; i < 512; i += 256) sh2[i] = S1p[b * SROW + SH2 + i];
  __syncthreads();
  int to = tid >> 1, ks = tid & 1;
  float a = 0.f;
  if (to < OUTD) {
    const float* wr = Wo + to * HH + ks * 256;
    const float* hr = &sh2[ks * 256];
    #pragma unroll 8
    for (int kk = 0; kk < 256; kk += 4) {
      float4 q = *reinterpret_cast<const float4*>(&wr[kk]);
      float4 h4 = *reinterpret_cast<const float4*>(&hr[kk]);
      a += q.x * h4.x + q.y * h4.y + q.z * h4.z + q.w * h4.w;
    }
  }
  a += __shfl_xor(a, 1);
  if (ks == 0 && to < OUTD) so[to] = a + bo[to];
  __syncthreads();
  mix_loss_block(so, y, b, 599, lossacc, tid);
}

__global__ void k_ep2(const float* __restrict__ lossacc, float* __restrict__ out)
{
  int tid = threadIdx.x;
  float v = lossacc[tid];
  #pragma unroll
  for (int d = 32; d >= 1; d >>= 1) v += __shfl_xor(v, d);
  if (tid == 0) out[0] = v / 38400.0f;
}

extern "C" void kernel_launch(void* const* d_in, const int* in_sizes, int n_in,
                              void* d_out, int out_size, void* d_ws, size_t ws_size,
                              hipStream_t stream)
{
  (void)in_sizes; (void)n_in; (void)out_size; (void)ws_size;
  const float* x    = (const float*)d_in[0];
  const float* y    = (const float*)d_in[1];
  const float* cvec = (const float*)d_in[2];
  const float* Wih1 = (const float*)d_in[3];
  const float* Whh1 = (const float*)d_in[4];
  const float* bih1 = (const float*)d_in[5];
  const float* bhh1 = (const float*)d_in[6];
  const float* Wih2 = (const float*)d_in[7];
  const float* Whh2 = (const float*)d_in[8];
  const float* bih2 = (const float*)d_in[9];
  const float* bhh2 = (const float*)d_in[10];
  const float* Wk   = (const float*)d_in[11];
  const float* bk   = (const float*)d_in[12];
  const float* Wo   = (const float*)d_in[13];
  const float* bo   = (const float*)d_in[14];

  float* ws   = (float*)d_ws;
  float* S0   = ws + OFF_S0;
  float* S1   = ws + OFF_S1;
  float* c1p  = ws + OFF_C1;
  float* c2p  = ws + OFF_C2;
  float* kapp = ws + OFF_KAP;
  float* losp = ws + OFF_LOSS;
  float* outb = ws + OFF_OUTB;
  float* w1p  = ws + OFF_W1P;
  float* w2p  = ws + OFF_W2P;

  k_init0<<<512, 256, 0, stream>>>(ws);
  k_init1<<<512, 256, 0, stream>>>(ws, x, Wih1, Wih2);

  for (int t = -1; t <= 599; ++t) {
    float* Scur = ((t + 1) & 1) ? S1 : S0;
    float* Snxt = ((t + 1) & 1) ? S0 : S1;
    k_alpha<<<256, 256, 0, stream>>>(t, Scur, Snxt, c1p, c2p, w1p, w2p, Whh1, Whh2,
                                     bih1, bhh1, bih2, bhh2, Wo, bo, outb);
    k_beta<<<128, 256, 0, stream>>>(t, x, y, cvec, Wk, bk, Snxt, kapp, outb, losp);
  }
  k_ep1<<<64, 256, 0, stream>>>(S1, Wo, bo, y, losp);
  k_ep2<<<1, 64, 0, stream>>>(losp, (float*)d_out);
}

// Round 2
// 46532.367 us; speedup vs baseline: 1.5359x; 1.5359x over previous
//
#include <hip/hip_runtime.h>
#include <hip/hip_cooperative_groups.h>
#include <math.h>

namespace cg = cooperative_groups;

typedef _Float16 h2v __attribute__((ext_vector_type(2)));
typedef _Float16 h4v __attribute__((ext_vector_type(4)));
union H4 { h4v v; h2v p[2]; };

#define NB 256
#define NT 256
#define NK4 272
#define ABE (NK4*256)   // 69632 f16 elems per parity buffer

__device__ __forceinline__ float fd2(h2v a, h2v b, float c) {
#if __has_builtin(__builtin_amdgcn_fdot2)
  return __builtin_amdgcn_fdot2(a, b, c, false);
#else
  return c + (float)a.x * (float)b.x + (float)a.y * (float)b.y;
#endif
}
__device__ __forceinline__ float sigm(float v) { return 1.0f / (1.0f + expf(-v)); }

struct G2S {                       // gates2 blocks (0..127)
  _Float16 w[16*1088];
  float bias[16];
  float ylds[1800];
  float so[124];
};
struct G1S {                       // gates1+attention blocks (128..191)
  _Float16 w[32*576];
  float bias[32];
  float cvec[64*54];
  float xl[1800];
  float h1loc[512];
  float skg[32], sal[12], sbe[12], ska[12], kap[12], sphi[64];
};
struct PRS {                       // projection blocks (192..255)
  _Float16 wo[2*512];
  float bos[2];
  float part[4*64];
};
union SM { G2S g2; G1S g1; PRS pr; };

__device__ __forceinline__ float mix_loss(const float* so, const float* yl, int t)
{
  const int m = threadIdx.x;   // caller guarantees m < 32
  float y1 = yl[t*3+0], y2 = yl[t*3+1], ys = yl[t*3+2];
  float ph = (m < 20) ? so[1+m] : -1e30f;
  float mx = ph;
  #pragma unroll
  for (int d = 16; d >= 1; d >>= 1) mx = fmaxf(mx, __shfl_xor(mx, d));
  float pe = (m < 20) ? expf(ph - mx) : 0.f;
  float ps = pe;
  #pragma unroll
  for (int d = 16; d >= 1; d >>= 1) ps += __shfl_xor(ps, d);
  float contrib = 0.f;
  if (m < 20) {
    float mu1 = so[21+m], mu2 = so[41+m];
    float s1 = expf(so[61+m]), s2 = expf(so[81+m]);
    float rh = tanhf(so[101+m]);
    float d1 = (y1-mu1)/s1, d2 = (y2-mu2)/s2;
    float omr = 1.f - rh*rh;
    float z = d1*d1 + d2*d2 - 2.f*rh*d1*d2;
    float ga = expf(-z/(2.f*omr)) / (6.283185307179586f * s1 * s2 * sqrtf(omr));
    contrib = (pe/ps)*ga;
  }
  float gs = contrib;
  #pragma unroll
  for (int d = 16; d >= 1; d >>= 1) gs += __shfl_xor(gs, d);
  float lg = -logf(gs + 1e-20f);
  float e = 1.f/(1.f + expf(so[0]));
  float lb = -logf((e + 1e-20f)*ys + (1.f - e + 1e-20f)*(1.f - ys));
  return lg + lb;
}

__global__ __launch_bounds__(NT, 1) void kmain(
    const float* __restrict__ x, const float* __restrict__ y, const float* __restrict__ cvec,
    const float* __restrict__ Wih1, const float* __restrict__ Whh1,
    const float* __restrict__ bih1, const float* __restrict__ bhh1,
    const float* __restrict__ Wih2, const float* __restrict__ Whh2,
    const float* __restrict__ bih2, const float* __restrict__ bhh2,
    const float* __restrict__ Wk, const float* __restrict__ bk,
    const float* __restrict__ Wo, const float* __restrict__ bo,
    float* __restrict__ out, float* __restrict__ ws)
{
  cg::grid_group grid = cg::this_grid();
  __shared__ SM sm;
  const int blk = blockIdx.x, tid = threadIdx.x;

  _Float16* AB = (_Float16*)ws;          // 2 * ABE f16 = 278528 B
  float* outg  = ws + 69632;             // 64*121 f32
  float* lossg = outg + 64*121;          // 64 f32

  // zero both A parity buffers (each block clears its 1088-byte slice)
  { uint32_t* z = (uint32_t*)ws;
    for (int d = tid; d < 272; d += NT) z[blk*272 + d] = 0u; }

  float c2reg = 0.f, c1regA = 0.f, c1regB = 0.f, lreg = 0.f;

  // ---- per-role LDS init ----
  if (blk < 128) {
    for (int e = tid; e < 16*1088; e += NT) {
      int r = e / 1088, c = e - r*1088;
      int R = (r >> 2)*512 + blk*4 + (r & 3);
      float v = 0.f;
      if (c >= 4 && c < 58)         v = Wih2[R*569 + 515 + (c-4)];   // w
      else if (c >= 60 && c < 572)  v = Wih2[R*569 + 3 + (c-60)];    // h1
      else if (c >= 572 && c < 575) v = Wih2[R*569 + (c-572)];       // x(t)
      else if (c >= 576)            v = Whh2[R*512 + (c-576)];       // h2
      sm.g2.w[e] = (_Float16)v;
    }
    if (tid < 16) {
      int R = (tid >> 2)*512 + blk*4 + (tid & 3);
      sm.g2.bias[tid] = bih2[R] + bhh2[R];
    }
    if (blk < 64)
      for (int e = tid; e < 1800; e += NT) sm.g2.ylds[e] = y[blk*1800 + e];
  } else if (blk < 192) {
    const int b1 = blk - 128;
    for (int e = tid; e < 32*576; e += NT) {
      int r = e / 576, c = e - r*576;
      int R = (r >> 3)*512 + b1*8 + (r & 7);
      float v = 0.f;
      if (c < 3)                    v = Wih1[R*57 + c];              // x(t)
      else if (c >= 4 && c < 58)    v = Wih1[R*57 + 3 + (c-4)];      // w
      else if (c >= 60 && c < 572)  v = Whh1[R*512 + (c-60)];        // h1
      sm.g1.w[e] = (_Float16)v;
    }
    if (tid < 32) {
      int R = (tid >> 3)*512 + b1*8 + (tid & 7);
      sm.g1.bias[tid] = bih1[R] + bhh1[R];
    }
    for (int e = tid; e < 64*54; e += NT) sm.g1.cvec[e] = cvec[b1*3456 + e];
    for (int e = tid; e < 1800; e += NT)  sm.g1.xl[e]   = x[b1*1800 + e];
    if (tid < 12) sm.g1.kap[tid] = 0.f;
  } else {
    const int b2 = blk - 192;
    for (int e = tid; e < 1024; e += NT) {
      int rr = e >> 9, row = b2*2 + rr;
      sm.pr.wo[e] = (row < 121) ? (_Float16)Wo[row*512 + (e & 511)] : (_Float16)0.f;
    }
    if (tid < 2) {
      int row = b2*2 + tid;
      sm.pr.bos[tid] = (row < 121) ? bo[row] : 0.f;
    }
  }
  grid.sync();
  // stage x(0) into buf0 xA slot (cols 0..2 -> k4=0)
  if (blk >= 128 && blk < 192 && tid < 3)
    AB[0*ABE + 0*256 + (blk-128)*4 + tid] = (_Float16)sm.g1.xl[tid];
  grid.sync();

  // ---- main recurrence: iterations i = 0..601 ----
  for (int i = 0; i <= 601; ++i) {
    const _Float16* __restrict__ Acur = AB + (i & 1)*ABE;
    _Float16* __restrict__ Anxt = AB + ((i & 1) ^ 1)*ABE;

    // ================= Phase A =================
    if (blk < 128) {
      if (i >= 1 && i <= 600) {              // gates2(i-1)
        const int hd = tid >> 6, b = tid & 63;
        const _Float16* __restrict__ Ap = Acur + b*4;
        const _Float16* __restrict__ wp = &sm.g2.w[hd*1088];
        float a0 = 0.f, a1 = 0.f, a2 = 0.f, a3 = 0.f;
        #pragma unroll 4
        for (int k4 = 0; k4 < 272; ++k4) {
          H4 a;  a.v  = *(const h4v*)(Ap + k4*256);
          H4 q0; q0.v = *(const h4v*)(wp + k4*4);
          H4 q1; q1.v = *(const h4v*)(wp + 4352  + k4*4);
          H4 q2; q2.v = *(const h4v*)(wp + 8704  + k4*4);
          H4 q3; q3.v = *(const h4v*)(wp + 13056 + k4*4);
          a0 = fd2(a.p[0], q0.p[0], a0); a0 = fd2(a.p[1], q0.p[1], a0);
          a1 = fd2(a.p[0], q1.p[0], a1); a1 = fd2(a.p[1], q1.p[1], a1);
          a2 = fd2(a.p[0], q2.p[0], a2); a2 = fd2(a.p[1], q2.p[1], a2);
          a3 = fd2(a.p[0], q3.p[0], a3); a3 = fd2(a.p[1], q3.p[1], a3);
        }
        float ig = sigm(a0 + sm.g2.bias[hd]);
        float fg = sigm(a1 + sm.g2.bias[4 + hd]);
        float gg = tanhf(a2 + sm.g2.bias[8 + hd]);
        float og = sigm(a3 + sm.g2.bias[12 + hd]);
        c2reg = fg * c2reg + ig * gg;
        float h2 = og * tanhf(c2reg);
        Anxt[(144 + blk)*256 + b*4 + hd] = (_Float16)h2;
      }
    } else if (blk < 192) {
      if (i <= 599) {                        // gates1(i)
        const int b1 = blk - 128;
        const int hd = tid >> 6, b = tid & 63;
        const _Float16* __restrict__ Ap  = Acur + b*4;
        const _Float16* __restrict__ wpA = &sm.g1.w[hd*576];
        const _Float16* __restrict__ wpB = wpA + 4*576;
        float accA0=0.f,accA1=0.f,accA2=0.f,accA3=0.f;
        float accB0=0.f,accB1=0.f,accB2=0.f,accB3=0.f;
        #pragma unroll 2
        for (int k4 = 0; k4 < 144; ++k4) {
          H4 a; a.v = *(const h4v*)(Ap + k4*256);
          H4 qa0; qa0.v = *(const h4v*)(wpA + k4*4);
          H4 qa1; qa1.v = *(const h4v*)(wpA + 4608  + k4*4);
          H4 qa2; qa2.v = *(const h4v*)(wpA + 9216  + k4*4);
          H4 qa3; qa3.v = *(const h4v*)(wpA + 13824 + k4*4);
          H4 qb0; qb0.v = *(const h4v*)(wpB + k4*4);
          H4 qb1; qb1.v = *(const h4v*)(wpB + 4608  + k4*4);
          H4 qb2; qb2.v = *(const h4v*)(wpB + 9216  + k4*4);
          H4 qb3; qb3.v = *(const h4v*)(wpB + 13824 + k4*4);
          accA0 = fd2(a.p[0], qa0.p[0], accA0); accA0 = fd2(a.p[1], qa0.p[1], accA0);
          accA1 = fd2(a.p[0], qa1.p[0], accA1); accA1 = fd2(a.p[1], qa1.p[1], accA1);
          accA2 = fd2(a.p[0], qa2.p[0], accA2); accA2 = fd2(a.p[1], qa2.p[1], accA2);
          accA3 = fd2(a.p[0], qa3.p[0], accA3); accA3 = fd2(a.p[1], qa3.p[1], accA3);
          accB0 = fd2(a.p[0], qb0.p[0], accB0); accB0 = fd2(a.p[1], qb0.p[1], accB0);
          accB1 = fd2(a.p[0], qb1.p[0], accB1); accB1 = fd2(a.p[1], qb1.p[1], accB1);
          accB2 = fd2(a.p[0], qb2.p[0], accB2); accB2 = fd2(a.p[1], qb2.p[1], accB2);
          accB3 = fd2(a.p[0], qb3.p[0], accB3); accB3 = fd2(a.p[1], qb3.p[1], accB3);
        }
        {
          int D = b1*8 + hd;
          float ig = sigm(accA0 + sm.g1.bias[hd]);
          float fg = sigm(accA1 + sm.g1.bias[8 + hd]);
          float gg = tanhf(accA2 + sm.g1.bias[16 + hd]);
          float og = sigm(accA3 + sm.g1.bias[24 + hd]);
          c1regA = fg * c1regA + ig * gg;
          float h1 = og * tanhf(c1regA);
          Anxt[(15 + (D >> 2))*256 + b*4 + (D & 3)] = (_Float16)h1;
        }
        {
          int D = b1*8 + hd + 4;
          float ig = sigm(accB0 + sm.g1.bias[hd + 4]);
          float fg = sigm(accB1 + sm.g1.bias[12 + hd]);
          float gg = tanhf(accB2 + sm.g1.bias[20 + hd]);
          float og = sigm(accB3 + sm.g1.bias[28 + hd]);
          c1regB = fg * c1regB + ig * gg;
          float h1 = og * tanhf(c1regB);
          Anxt[(15 + (D >> 2))*256 + b*4 + (D & 3)] = (_Float16)h1;
        }
      }
    } else {
      if (i >= 2) {                          // proj(i-2)
        const int b2 = blk - 192;
        const int wv = tid >> 6, b = tid & 63;
        const int rsel = wv >> 1, ksel = wv & 1;
        const int row = b2*2 + rsel;
        float a = 0.f;
        if (row < 121) {
          const _Float16* __restrict__ wo = &sm.pr.wo[rsel*512 + ksel*256];
          const _Float16* __restrict__ Ap = Acur + (144 + ksel*64)*256 + b*4;
          #pragma unroll 4
          for (int k4 = 0; k4 < 64; ++k4) {
            H4 av; av.v = *(const h4v*)(Ap + k4*256);
            H4 qv; qv.v = *(const h4v*)(wo + k4*4);
            a = fd2(av.p[0], qv.p[0], a); a = fd2(av.p[1], qv.p[1], a);
          }
        }
        sm.pr.part[wv*64 + b] = a;
        __syncthreads();
        if (tid < 128) {
          int rr = tid >> 6, bb = tid & 63;
          int row2 = b2*2 + rr;
          if (row2 < 121) {
            float s = sm.pr.part[(rr*2)*64 + bb] + sm.pr.part[(rr*2+1)*64 + bb];
            outg[bb*121 + row2] = s + sm.pr.bos[rr];
          }
        }
      }
    }
    grid.sync();

    // ================= Phase B =================
    if (blk >= 128 && blk < 192) {
      if (i <= 599) {                        // attention(i): h1(i) -> w(i)
        const int b1 = blk - 128;
        for (int d = tid; d < 512; d += NT)
          sm.g1.h1loc[d] = (float)Anxt[(15 + (d >> 2))*256 + b1*4 + (d & 3)];
        __syncthreads();
        {
          const int j = tid >> 3, ksv = tid & 7;
          float a = 0.f;
          if (j < 30) {
            const float* __restrict__ wk = Wk + j*512 + ksv*64;
            const float* __restrict__ hh = &sm.g1.h1loc[ksv*64];
            #pragma unroll 8
            for (int kk = 0; kk < 64; kk += 4) {
              float4 q = *(const float4*)(wk + kk);
              float4 h = *(const float4*)(hh + kk);
              a += q.x*h.x + q.y*h.y + q.z*h.z + q.w*h.w;
            }
          }
          a += __shfl_xor(a, 1); a += __shfl_xor(a, 2); a += __shfl_xor(a, 4);
          if (j < 30 && ksv == 0) sm.g1.skg[j] = a + bk[j];
        }
        __syncthreads();
        if (tid < 10) {
          sm.g1.sal[tid] = expf(sm.g1.skg[tid]);
          sm.g1.sbe[tid] = expf(sm.g1.skg[10 + tid]);
          float kp = sm.g1.kap[tid] + expf(sm.g1.skg[20 + tid]);
          sm.g1.kap[tid] = kp;
          sm.g1.ska[tid] = kp;
        }
        __syncthreads();
        if (tid < 64) {
          float u = (float)tid, ph = 0.f;
          #pragma unroll
          for (int k = 0; k < 10; ++k) {
            float d = sm.g1.ska[k] - u;
            ph += sm.g1.sal[k] * expf(-sm.g1.sbe[k] * d * d);
          }
          sm.g1.sphi[tid] = ph;
        }
        __syncthreads();
        if (tid < 54) {
          float wv2 = 0.f;
          #pragma unroll 4
          for (int u = 0; u < 64; ++u) wv2 += sm.g1.sphi[u] * sm.g1.cvec[u*54 + tid];
          int c = 4 + tid;
          Anxt[(c >> 2)*256 + b1*4 + (c & 3)] = (_Float16)wv2;
        } else if (tid < 57) {
          int jj = tid - 54;                 // xB = x(i), cols 572..574
          Anxt[143*256 + b1*4 + jj] = (_Float16)sm.g1.xl[i*3 + jj];
        } else if (tid < 60) {
          if (i <= 598) {
            int jj = tid - 57;               // xA = x(i+1), cols 0..2
            Anxt[0*256 + b1*4 + jj] = (_Float16)sm.g1.xl[(i+1)*3 + jj];
          }
        }
      }
    } else if (blk < 64) {
      if (i >= 2) {                          // loss(i-2)
        const int t = i - 2;
        for (int e = tid; e < 121; e += NT) sm.g2.so[e] = outg[blk*121 + e];
        __syncthreads();
        if (tid < 32) {
          float v = mix_loss(sm.g2.so, sm.g2.ylds, t);
          if (tid == 0) lreg += v;
        }
      }
    }
    grid.sync();
  }

  // ---- final reduction ----
  if (blk < 64 && tid == 0) lossg[blk] = lreg;
  grid.sync();
  if (blk == 0 && tid < 64) {
    float v = lossg[tid];
    #pragma unroll
    for (int d = 32; d >= 1; d >>= 1) v += __shfl_xor(v, d);
    if (tid == 0) out[0] = v / 38400.f;
  }
}

extern "C" void kernel_launch(void* const* d_in, const int* in_sizes, int n_in,
                              void* d_out, int out_size, void* d_ws, size_t ws_size,
                              hipStream_t stream)
{
  (void)in_sizes; (void)n_in; (void)out_size; (void)ws_size;
  const float* x    = (const float*)d_in[0];
  const float* y    = (const float*)d_in[1];
  const float* cvec = (const float*)d_in[2];
  const float* Wih1 = (const float*)d_in[3];
  const float* Whh1 = (const float*)d_in[4];
  const float* bih1 = (const float*)d_in[5];
  const float* bhh1 = (const float*)d_in[6];
  const float* Wih2 = (const float*)d_in[7];
  const float* Whh2 = (const float*)d_in[8];
  const float* bih2 = (const float*)d_in[9];
  const float* bhh2 = (const float*)d_in[10];
  const float* Wk   = (const float*)d_in[11];
  const float* bk   = (const float*)d_in[12];
  const float* Wo   = (const float*)d_in[13];
  const float* bo   = (const float*)d_in[14];
  float* out = (float*)d_out;
  float* wsf = (float*)d_ws;

  void* args[] = {
    (void*)&x, (void*)&y, (void*)&cvec,
    (void*)&Wih1, (void*)&Whh1, (void*)&bih1, (void*)&bhh1,
    (void*)&Wih2, (void*)&Whh2, (void*)&bih2, (void*)&bhh2,
    (void*)&Wk, (void*)&bk, (void*)&Wo, (void*)&bo,
    (void*)&out, (void*)&wsf
  };
  hipLaunchCooperativeKernel((void*)kmain, dim3(NB), dim3(NT), args, 0, stream);
}

// Round 3
// 16714.084 us; speedup vs baseline: 4.2759x; 2.7840x over previous
//
#include <hip/hip_runtime.h>
#include <math.h>

typedef _Float16 f16;
typedef _Float16 f16x8 __attribute__((ext_vector_type(8)));
typedef _Float16 f16x2 __attribute__((ext_vector_type(2)));
typedef float f32x4 __attribute__((ext_vector_type(4)));
union F16x8 { f16x8 v; f16x2 p[4]; };

#define NT 512
#define AROW 1088
#define ABE 69632              // f16 elements per parity buffer (64*1088)
#define PH_STRIDE 144          // uints per barrier phase slot
#define NPH 1206
#define OUTG_OFF 69632         // float offset in ws
#define LOSS_OFF 77824         // float offset
#define BAR_OFF  78080         // uint offset

__device__ __forceinline__ float fd2(f16x2 a, f16x2 b, float c) {
#if __has_builtin(__builtin_amdgcn_fdot2)
  return __builtin_amdgcn_fdot2(a, b, c, false);
#else
  return c + (float)a.x*(float)b.x + (float)a.y*(float)b.y;
#endif
}
__device__ __forceinline__ float sigm(float v){ return 1.f/(1.f+expf(-v)); }

struct G2S { f16 w[16*1088]; float part[2][64][17]; };
struct G1S { f16 w1[32*576]; float part[2][64][33]; f16 wo[2*512]; float pp[64*16]; float bo2[2]; };
struct ATS { f16 wk[30*512]; float cv[3456]; float xl[1800]; float yl[1800];
             f16 h1h[512]; float so[124]; float skg[32];
             float sal[10], sbe[10], kap[10]; float sphi[64]; float bkl[30]; };
union SM { G2S g2; G1S g1; ATS at; };

__device__ __forceinline__ void gbar(unsigned* bar, int p) {
  __syncthreads();
  if (threadIdx.x == 0) {
    __builtin_amdgcn_fence(__ATOMIC_RELEASE, "agent");
    unsigned* base = bar + p * PH_STRIDE;
    unsigned a = __hip_atomic_fetch_add(base + (blockIdx.x & 7) * 16, 1u,
                                        __ATOMIC_RELAXED, __HIP_MEMORY_SCOPE_AGENT);
    if (a == 31u)
      __hip_atomic_fetch_add(base + 128, 1u, __ATOMIC_RELAXED, __HIP_MEMORY_SCOPE_AGENT);
    while (__hip_atomic_load(base + 128, __ATOMIC_RELAXED, __HIP_MEMORY_SCOPE_AGENT) < 8u) {}
    __builtin_amdgcn_fence(__ATOMIC_ACQUIRE, "agent");
  }
  __syncthreads();
}

__device__ __forceinline__ float mix_loss(const float* so, const float* yl, int t, int m) {
  float y1 = yl[t*3+0], y2 = yl[t*3+1], ys = yl[t*3+2];
  float ph = (m < 20) ? so[1+m] : -1e30f;
  float mx = ph;
  #pragma unroll
  for (int d = 16; d >= 1; d >>= 1) mx = fmaxf(mx, __shfl_xor(mx, d));
  float pe = (m < 20) ? expf(ph - mx) : 0.f;
  float ps = pe;
  #pragma unroll
  for (int d = 16; d >= 1; d >>= 1) ps += __shfl_xor(ps, d);
  float contrib = 0.f;
  if (m < 20) {
    float mu1 = so[21+m], mu2 = so[41+m];
    float s1 = expf(so[61+m]), s2 = expf(so[81+m]);
    float rh = tanhf(so[101+m]);
    float d1 = (y1-mu1)/s1, d2 = (y2-mu2)/s2;
    float omr = 1.f - rh*rh;
    float z = d1*d1 + d2*d2 - 2.f*rh*d1*d2;
    float ga = expf(-z/(2.f*omr)) / (6.283185307179586f * s1 * s2 * sqrtf(omr));
    contrib = (pe/ps)*ga;
  }
  float gs = contrib;
  #pragma unroll
  for (int d = 16; d >= 1; d >>= 1) gs += __shfl_xor(gs, d);
  float lg = -logf(gs + 1e-20f);
  float e = 1.f/(1.f + expf(so[0]));
  float lb = -logf((e + 1e-20f)*ys + (1.f - e + 1e-20f)*(1.f - ys));
  return lg + lb;
}

__global__ __launch_bounds__(256) void k_init(float* ws) {
  unsigned* w0 = (unsigned*)ws;                 // A buffers: 278528 B = 69632 words
  unsigned* wb = (unsigned*)ws + BAR_OFF;       // barrier slots
  int idx = blockIdx.x*256 + threadIdx.x;
  int str = gridDim.x*256;
  for (int e = idx; e < 69632; e += str) w0[e] = 0u;
  for (int e = idx; e < NPH*PH_STRIDE; e += str) wb[e] = 0u;
}

__global__ __launch_bounds__(NT, 1) void kmain(
    const float* __restrict__ x, const float* __restrict__ y, const float* __restrict__ cvec,
    const float* __restrict__ Wih1, const float* __restrict__ Whh1,
    const float* __restrict__ bih1, const float* __restrict__ bhh1,
    const float* __restrict__ Wih2, const float* __restrict__ Whh2,
    const float* __restrict__ bih2, const float* __restrict__ bhh2,
    const float* __restrict__ Wk, const float* __restrict__ bk,
    const float* __restrict__ Wo, const float* __restrict__ bo,
    float* __restrict__ out, float* __restrict__ ws)
{
  const int blk = blockIdx.x, tid = threadIdx.x;
  const int wv = tid >> 6, l = tid & 63;
  __shared__ SM sm;

  f16* AB = (f16*)ws;
  float* outg  = ws + OUTG_OFF;     // [64][128] f32
  float* lossg = ws + LOSS_OFF;     // [64] f32
  unsigned* bar = (unsigned*)ws + BAR_OFF;

  float c_st = 0.f, lreg = 0.f;
  float bias_r[4] = {0.f,0.f,0.f,0.f};

  // ---------------- per-role init ----------------
  if (blk < 128) {                       // gates2: h-dims blk*4 .. +4, rows n = gate*4+hd
    for (int n = 0; n < 16; ++n) {
      int R = (n >> 2)*512 + blk*4 + (n & 3);
      for (int k = tid; k < 1088; k += NT) {
        float v;
        if (k < 3) v = 0.f;                            // xA (unused by gates2)
        else if (k < 57) v = Wih2[R*569 + 515 + (k-3)];   // w
        else if (k < 60) v = Wih2[R*569 + (k-57)];        // xB = x(t)
        else if (k < 64) v = 0.f;                      // pad
        else if (k < 576) v = Wih2[R*569 + 3 + (k-64)];   // h1
        else v = Whh2[R*512 + (k-576)];                // h2
        int idx = n*1088 + k;
        sm.g2.w[idx ^ ((n & 7) << 3)] = (f16)v;
      }
    }
    if (tid < 256) {
      int hd = tid >> 6;
      #pragma unroll
      for (int g = 0; g < 4; ++g) {
        int R = g*512 + blk*4 + hd;
        bias_r[g] = bih2[R] + bhh2[R];
      }
    }
  } else if (blk < 192) {                // gates1 + proj: h-dims (blk-128)*8
    const int g1i = blk - 128;
    for (int n = 0; n < 32; ++n) {
      int R = (n >> 3)*512 + g1i*8 + (n & 7);
      for (int k = tid; k < 576; k += NT) {
        float v;
        if (k < 57) v = Wih1[R*57 + k];        // [xA | w] matches Wih1 cols directly
        else if (k < 64) v = 0.f;              // xB+pad (zero weights)
        else v = Whh1[R*512 + (k-64)];         // h1
        int idx = n*576 + k;
        sm.g1.w1[idx ^ ((n & 7) << 3)] = (f16)v;
      }
    }
    for (int r = 0; r < 2; ++r) {
      int row = g1i*2 + r;
      for (int k = tid; k < 512; k += NT)
        sm.g1.wo[r*512 + k] = (row < 121) ? (f16)Wo[row*512 + k] : (f16)0.f;
    }
    { int hd = tid >> 6;
      #pragma unroll
      for (int g = 0; g < 4; ++g) {
        int R = g*512 + g1i*8 + hd;
        bias_r[g] = bih1[R] + bhh1[R];
      } }
    if (tid < 2) { int row = g1i*2 + tid; sm.g1.bo2[tid] = (row < 121) ? bo[row] : 0.f; }
  } else {                               // attention + loss: batch b = blk-192
    const int b = blk - 192;
    for (int e = tid; e < 30*512; e += NT) sm.at.wk[e] = (f16)Wk[e];
    for (int e = tid; e < 3456; e += NT) sm.at.cv[e] = cvec[b*3456 + e];
    for (int e = tid; e < 1800; e += NT) { sm.at.xl[e] = x[b*1800+e]; sm.at.yl[e] = y[b*1800+e]; }
    if (tid < 30) sm.at.bkl[tid] = bk[tid];
    if (tid < 10) sm.at.kap[tid] = 0.f;
    __syncthreads();
    if (tid < 3) AB[b*1088 + tid] = (f16)sm.at.xl[tid];    // xA(0) into parity-0
  }

  gbar(bar, 0);

  // ---------------- main recurrence ----------------
  for (int i = 0; i <= 601; ++i) {
    const f16* __restrict__ Acur = AB + (i & 1)*ABE;
    f16* __restrict__ Anxt = AB + ((i & 1)^1)*ABE;

    // ============ Phase A ============
    if (blk < 128) {
      if (i >= 1 && i <= 600) {                    // gates2 -> h2(i-1)
        const int mt = wv & 3, kh = wv >> 2;
        const int mA = mt*16 + (l & 15);
        const int kb = (l >> 4)*8;
        const int n = l & 15;
        f32x4 acc = {0.f,0.f,0.f,0.f};
        const f16* __restrict__ Ap = Acur + mA*1088;
        #pragma unroll 4
        for (int j = 0; j < 17; ++j) {
          int k = kh*544 + j*32 + kb;
          f16x8 af = *(const f16x8*)(Ap + k);
          f16x8 bf = *(const f16x8*)&sm.g2.w[(n*1088 + k) ^ ((n & 7) << 3)];
          acc = __builtin_amdgcn_mfma_f32_16x16x32_f16(af, bf, acc, 0, 0, 0);
        }
        #pragma unroll
        for (int r = 0; r < 4; ++r)
          sm.g2.part[kh][mt*16 + (l>>4)*4 + r][n] = acc[r];
        __syncthreads();
        if (tid < 256) {
          int b_ = tid & 63, hd = tid >> 6;
          float gi_ = sm.g2.part[0][b_][hd]     + sm.g2.part[1][b_][hd]     + bias_r[0];
          float gf_ = sm.g2.part[0][b_][4+hd]   + sm.g2.part[1][b_][4+hd]   + bias_r[1];
          float gg_ = sm.g2.part[0][b_][8+hd]   + sm.g2.part[1][b_][8+hd]   + bias_r[2];
          float go_ = sm.g2.part[0][b_][12+hd]  + sm.g2.part[1][b_][12+hd]  + bias_r[3];
          float ig = sigm(gi_), fg = sigm(gf_), gg2 = tanhf(gg_), og = sigm(go_);
          c_st = fg*c_st + ig*gg2;
          Anxt[b_*1088 + 576 + blk*4 + hd] = (f16)(og * tanhf(c_st));
        }
      }
    } else if (blk < 192) {
      const int g1i = blk - 128;
      if (i <= 599) {                              // gates1 -> h1(i)
        const int mt = wv & 3, kh = wv >> 2;
        const int mA = mt*16 + (l & 15);
        const int kb = (l >> 4)*8;
        const int n = l & 15;
        f32x4 acc0 = {0.f,0.f,0.f,0.f}, acc1 = {0.f,0.f,0.f,0.f};
        const f16* __restrict__ Ap = Acur + mA*1088;
        #pragma unroll 3
        for (int j = 0; j < 9; ++j) {
          int k = kh*288 + j*32 + kb;
          f16x8 af = *(const f16x8*)(Ap + k);
          f16x8 b0 = *(const f16x8*)&sm.g1.w1[(n*576 + k) ^ ((n & 7) << 3)];
          f16x8 b1 = *(const f16x8*)&sm.g1.w1[((n+16)*576 + k) ^ (((n+16) & 7) << 3)];
          acc0 = __builtin_amdgcn_mfma_f32_16x16x32_f16(af, b0, acc0, 0, 0, 0);
          acc1 = __builtin_amdgcn_mfma_f32_16x16x32_f16(af, b1, acc1, 0, 0, 0);
        }
        #pragma unroll
        for (int r = 0; r < 4; ++r) {
          int m = mt*16 + (l>>4)*4 + r;
          sm.g1.part[kh][m][n]    = acc0[r];
          sm.g1.part[kh][m][16+n] = acc1[r];
        }
        __syncthreads();
        {
          int b_ = tid & 63, hd = tid >> 6;
          float gi_ = sm.g1.part[0][b_][hd]     + sm.g1.part[1][b_][hd]     + bias_r[0];
          float gf_ = sm.g1.part[0][b_][8+hd]   + sm.g1.part[1][b_][8+hd]   + bias_r[1];
          float gg_ = sm.g1.part[0][b_][16+hd]  + sm.g1.part[1][b_][16+hd]  + bias_r[2];
          float go_ = sm.g1.part[0][b_][24+hd]  + sm.g1.part[1][b_][24+hd]  + bias_r[3];
          float ig = sigm(gi_), fg = sigm(gf_), gg2 = tanhf(gg_), og = sigm(go_);
          c_st = fg*c_st + ig*gg2;
          Anxt[b_*1088 + 64 + g1i*8 + hd] = (f16)(og * tanhf(c_st));
        }
      }
      if (i >= 2) {                                // proj(i-2) from h2 panel in Acur
        int b_ = tid & 63, ks = tid >> 6;
        float p0 = 0.f, p1 = 0.f;
        const f16* __restrict__ Ah = Acur + b_*1088 + 576 + ks*64;
        #pragma unroll
        for (int c = 0; c < 8; ++c) {
          F16x8 av;  av.v  = *(const f16x8*)(Ah + c*8);
          F16x8 w0;  w0.v  = *(const f16x8*)&sm.g1.wo[ks*64 + c*8];
          F16x8 w1_; w1_.v = *(const f16x8*)&sm.g1.wo[512 + ks*64 + c*8];
          #pragma unroll
          for (int q = 0; q < 4; ++q) {
            p0 = fd2(av.p[q], w0.p[q], p0);
            p1 = fd2(av.p[q], w1_.p[q], p1);
          }
        }
        sm.g1.pp[b_*16 + ks*2 + 0] = p0;
        sm.g1.pp[b_*16 + ks*2 + 1] = p1;
        __syncthreads();
        if (tid < 128) {
          int b2 = tid & 63, r = tid >> 6;
          int o = g1i*2 + r;
          if (o < 121) {
            float s = 0.f;
            #pragma unroll
            for (int k2 = 0; k2 < 8; ++k2) s += sm.g1.pp[b2*16 + k2*2 + r];
            outg[b2*128 + o] = s + sm.g1.bo2[r];
          }
        }
      }
    }
    gbar(bar, 1 + 2*i);

    // ============ Phase B ============
    if (blk >= 192) {
      const int b = blk - 192;
      if (i <= 599) {                              // attention(i): h1(i) -> w(i)
        sm.at.h1h[tid] = Anxt[b*1088 + 64 + tid];
        __syncthreads();
        {
          int j = tid >> 4, ksv = tid & 15;
          float a = 0.f;
          if (j < 30) {
            #pragma unroll
            for (int c = 0; c < 4; ++c) {
              F16x8 hv;  hv.v  = *(const f16x8*)&sm.at.h1h[ksv*32 + c*8];
              F16x8 wv_; wv_.v = *(const f16x8*)&sm.at.wk[j*512 + ksv*32 + c*8];
              #pragma unroll
              for (int q = 0; q < 4; ++q) a = fd2(hv.p[q], wv_.p[q], a);
            }
          }
          a += __shfl_xor(a, 1); a += __shfl_xor(a, 2);
          a += __shfl_xor(a, 4); a += __shfl_xor(a, 8);
          if (j < 30 && ksv == 0) sm.at.skg[j] = a + sm.at.bkl[j];
        }
        __syncthreads();
        if (tid < 10) {
          sm.at.sal[tid] = expf(sm.at.skg[tid]);
          sm.at.sbe[tid] = expf(sm.at.skg[10+tid]);
          sm.at.kap[tid] += expf(sm.at.skg[20+tid]);
        }
        __syncthreads();
        if (tid < 64) {
          float u = (float)tid, ph = 0.f;
          #pragma unroll
          for (int k2 = 0; k2 < 10; ++k2) {
            float d = sm.at.kap[k2] - u;
            ph += sm.at.sal[k2]*expf(-sm.at.sbe[k2]*d*d);
          }
          sm.at.sphi[tid] = ph;
        }
        __syncthreads();
        if (tid < 54) {
          float wvv = 0.f;
          #pragma unroll 8
          for (int u = 0; u < 64; ++u) wvv += sm.at.sphi[u]*sm.at.cv[u*54 + tid];
          Anxt[b*1088 + 3 + tid] = (f16)wvv;
        } else if (tid >= 54 && tid < 57) {
          Anxt[b*1088 + 57 + (tid-54)] = (f16)sm.at.xl[i*3 + (tid-54)];     // xB = x(i)
        } else if (tid >= 57 && tid < 60) {
          if (i <= 598)
            Anxt[b*1088 + (tid-57)] = (f16)sm.at.xl[(i+1)*3 + (tid-57)];    // xA = x(i+1)
        }
      }
      if (i >= 2) {                                // loss(i-2)
        if (tid < 121) sm.at.so[tid] = outg[b*128 + tid];
        __syncthreads();
        if (tid < 32) {
          float v = mix_loss(&sm.at.so[0], sm.at.yl, i-2, tid);
          if (tid == 0) lreg += v;
        }
      }
    }
    gbar(bar, 2 + 2*i);
  }

  if (blk >= 192 && tid == 0) lossg[blk - 192] = lreg;
  gbar(bar, 1205);
  if (blk == 192 && tid < 64) {
    float v = lossg[tid];
    #pragma unroll
    for (int d = 32; d >= 1; d >>= 1) v += __shfl_xor(v, d);
    if (tid == 0) out[0] = v / 38400.f;
  }
}

extern "C" void kernel_launch(void* const* d_in, const int* in_sizes, int n_in,
                              void* d_out, int out_size, void* d_ws, size_t ws_size,
                              hipStream_t stream)
{
  (void)in_sizes; (void)n_in; (void)out_size; (void)ws_size;
  const float* x    = (const float*)d_in[0];
  const float* y    = (const float*)d_in[1];
  const float* cvec = (const float*)d_in[2];
  const float* Wih1 = (const float*)d_in[3];
  const float* Whh1 = (const float*)d_in[4];
  const float* bih1 = (const float*)d_in[5];
  const float* bhh1 = (const float*)d_in[6];
  const float* Wih2 = (const float*)d_in[7];
  const float* Whh2 = (const float*)d_in[8];
  const float* bih2 = (const float*)d_in[9];
  const float* bhh2 = (const float*)d_in[10];
  const float* Wk   = (const float*)d_in[11];
  const float* bk   = (const float*)d_in[12];
  const float* Wo   = (const float*)d_in[13];
  const float* bo   = (const float*)d_in[14];
  float* out = (float*)d_out;
  float* wsf = (float*)d_ws;

  k_init<<<512, 256, 0, stream>>>(wsf);

  void* args[] = {
    (void*)&x, (void*)&y, (void*)&cvec,
    (void*)&Wih1, (void*)&Whh1, (void*)&bih1, (void*)&bhh1,
    (void*)&Wih2, (void*)&Whh2, (void*)&bih2, (void*)&bhh2,
    (void*)&Wk, (void*)&bk, (void*)&Wo, (void*)&bo,
    (void*)&out, (void*)&wsf
  };
  hipLaunchCooperativeKernel((void*)kmain, dim3(256), dim3(NT), args, 0, stream);
}

// Round 4
// 10709.364 us; speedup vs baseline: 6.6734x; 1.5607x over previous
//
#include <hip/hip_runtime.h>
#include <math.h>

typedef _Float16 f16;
typedef _Float16 f16x8 __attribute__((ext_vector_type(8)));
typedef float f32x4 __attribute__((ext_vector_type(4)));
union AFU { unsigned long long q[2]; f16x8 v; };
union HU { f16 h; unsigned short u; };

#define NT 512
#define NBLK 160            // 64 g2 + 32 g1 + 64 at
#define AROW 1088
#define ABE 69632           // f16 per parity buffer (64*1088)
#define OUTG_OFF 69632      // float offset
#define LOSS_OFF 77824
#define BAR_OFF  78080      // uint offset
#define PH_STRIDE 144
#define NPH 1206
#define DYN_LDS 132096

__device__ __forceinline__ unsigned long long ald64(const void* p) {
  return __hip_atomic_load((const unsigned long long*)p, __ATOMIC_RELAXED, __HIP_MEMORY_SCOPE_AGENT);
}
__device__ __forceinline__ unsigned ald32(const void* p) {
  return __hip_atomic_load((const unsigned*)p, __ATOMIC_RELAXED, __HIP_MEMORY_SCOPE_AGENT);
}
__device__ __forceinline__ void ast32(void* p, unsigned v) {
  __hip_atomic_store((unsigned*)p, v, __ATOMIC_RELAXED, __HIP_MEMORY_SCOPE_AGENT);
}
__device__ __forceinline__ float sigm(float v){ return 1.f/(1.f+expf(-v)); }

__device__ __forceinline__ void gbar(unsigned* bar, int p) {
  asm volatile("s_waitcnt vmcnt(0)" ::: "memory");
  __syncthreads();
  if (threadIdx.x == 0) {
    unsigned* base = bar + p * PH_STRIDE;
    unsigned a = __hip_atomic_fetch_add(base + (blockIdx.x & 7) * 16, 1u,
                                        __ATOMIC_RELAXED, __HIP_MEMORY_SCOPE_AGENT);
    if (a == 19u)   // 160 blocks / 8 sub-counters = 20 each
      __hip_atomic_fetch_add(base + 128, 1u, __ATOMIC_RELAXED, __HIP_MEMORY_SCOPE_AGENT);
    while (__hip_atomic_load(base + 128, __ATOMIC_RELAXED, __HIP_MEMORY_SCOPE_AGENT) < 8u) {}
  }
  __syncthreads();
}

__device__ __forceinline__ float mix_loss(const float* so, const float* yl, int t, int m) {
  float y1 = yl[t*3+0], y2 = yl[t*3+1], ys = yl[t*3+2];
  float ph = (m < 20) ? so[1+m] : -1e30f;
  float mx = ph;
  #pragma unroll
  for (int d = 16; d >= 1; d >>= 1) mx = fmaxf(mx, __shfl_xor(mx, d));
  float pe = (m < 20) ? expf(ph - mx) : 0.f;
  float ps = pe;
  #pragma unroll
  for (int d = 16; d >= 1; d >>= 1) ps += __shfl_xor(ps, d);
  float contrib = 0.f;
  if (m < 20) {
    float mu1 = so[21+m], mu2 = so[41+m];
    float s1 = expf(so[61+m]), s2 = expf(so[81+m]);
    float rh = tanhf(so[101+m]);
    float d1 = (y1-mu1)/s1, d2 = (y2-mu2)/s2;
    float omr = 1.f - rh*rh;
    float z = d1*d1 + d2*d2 - 2.f*rh*d1*d2;
    float ga = expf(-z/(2.f*omr)) / (6.283185307179586f * s1 * s2 * sqrtf(omr));
    contrib = (pe/ps)*ga;
  }
  float gs = contrib;
  #pragma unroll
  for (int d = 16; d >= 1; d >>= 1) gs += __shfl_xor(gs, d);
  float lg = -logf(gs + 1e-20f);
  float e = 1.f/(1.f + expf(so[0]));
  float lb = -logf((e + 1e-20f)*ys + (1.f - e + 1e-20f)*(1.f - ys));
  return lg + lb;
}

__global__ __launch_bounds__(256) void k_init(float* ws) {
  unsigned* w0 = (unsigned*)ws;
  unsigned* wb = (unsigned*)ws + BAR_OFF;
  int idx = blockIdx.x*256 + threadIdx.x;
  int str = gridDim.x*256;
  for (int e = idx; e < ABE; e += str) w0[e] = 0u;           // both A parity buffers (f16 pairs)
  for (int e = idx; e < NPH*PH_STRIDE; e += str) wb[e] = 0u; // barrier
}

__global__ __launch_bounds__(NT, 1) void kmain(
    const float* __restrict__ x, const float* __restrict__ y, const float* __restrict__ cvec,
    const float* __restrict__ Wih1, const float* __restrict__ Whh1,
    const float* __restrict__ bih1, const float* __restrict__ bhh1,
    const float* __restrict__ Wih2, const float* __restrict__ Whh2,
    const float* __restrict__ bih2, const float* __restrict__ bhh2,
    const float* __restrict__ Wk, const float* __restrict__ bk,
    const float* __restrict__ Wo, const float* __restrict__ bo,
    float* __restrict__ out, float* __restrict__ ws)
{
  extern __shared__ char dsm[];
  const int blk = blockIdx.x, tid = threadIdx.x;
  const int wv = tid >> 6, l = tid & 63;

  f16* AB = (f16*)ws;
  float* outg  = ws + OUTG_OFF;
  float* lossg = ws + LOSS_OFF;
  unsigned* bar = (unsigned*)ws + BAR_OFF;

  float lreg = 0.f;

  // ---------------- role init ----------------
  if (blk < 64) {
    // gates2 block: dims blk*8..+8 ; frag LDS [2 nt][34 j][64 l][8]
    f16* wf2 = (f16*)dsm;
    for (int f = tid; f < 2*34*64; f += NT) {
      int nt = f / (34*64), rem = f - nt*34*64, j = rem >> 6, lf = rem & 63;
      int nrow = nt*16 + (lf & 15);
      int R = (nrow >> 3)*512 + blk*8 + (nrow & 7);
      int kbase = j*32 + (lf >> 4)*8;
      #pragma unroll
      for (int e = 0; e < 8; ++e) {
        int k = kbase + e;
        float v = 0.f;
        if (k >= 4 && k < 58)        v = Wih2[R*569 + 515 + (k-4)];   // w
        else if (k >= 58 && k < 61)  v = Wih2[R*569 + (k-58)];        // xB
        else if (k >= 64 && k < 576) v = Wih2[R*569 + 3 + (k-64)];    // h1
        else if (k >= 576)           v = Whh2[R*512 + (k-576)];       // h2
        wf2[f*8 + e] = (f16)v;
      }
    }
  } else if (blk < 96) {
    const int g1i = blk - 64;
    f16* wf1  = (f16*)dsm;                    // [4 nt][18 j][64][8]
    f16* wofr = (f16*)(dsm + 73728);          // [16 j][64][8]
    for (int f = tid; f < 4*18*64; f += NT) {
      int nt = f / (18*64), rem = f - nt*18*64, j = rem >> 6, lf = rem & 63;
      int nrow = nt*16 + (lf & 15);
      int R = (nrow >> 4)*512 + g1i*16 + (nrow & 15);
      int kbase = j*32 + (lf >> 4)*8;
      #pragma unroll
      for (int e = 0; e < 8; ++e) {
        int k = kbase + e;
        float v = 0.f;
        if (k < 3)                   v = Wih1[R*57 + k];              // xA
        else if (k >= 4 && k < 58)   v = Wih1[R*57 + 3 + (k-4)];      // w
        else if (k >= 64 && k < 576) v = Whh1[R*512 + (k-64)];        // h1
        wf1[f*8 + e] = (f16)v;
      }
    }
    for (int f = tid; f < 16*64; f += NT) {
      int j = f >> 6, lf = f & 63;
      int nrow = lf & 15, row = g1i*4 + nrow;
      int kbase = j*32 + (lf >> 4)*8;
      #pragma unroll
      for (int e = 0; e < 8; ++e) {
        float v = (nrow < 4 && row < 121) ? Wo[row*512 + kbase + e] : 0.f;
        wofr[f*8 + e] = (f16)v;
      }
    }
  } else {
    const int b = blk - 96;
    f16*   wk  = (f16*)dsm;                  // [30][520]
    float* cv  = (float*)(dsm + 31200);
    float* xl  = (float*)(dsm + 45024);
    float* yl  = (float*)(dsm + 52224);
    for (int e = tid; e < 30*512; e += NT) { int j = e >> 9, k = e & 511; wk[j*520 + k] = (f16)Wk[e]; }
    for (int e = tid; e < 3456; e += NT) cv[e] = cvec[b*3456 + e];
    for (int e = tid; e < 1800; e += NT) { xl[e] = x[b*1800+e]; yl[e] = y[b*1800+e]; }
    float* kap = (float*)(dsm + 61152);
    if (tid < 10) kap[tid] = 0.f;
    __syncthreads();
    if (tid == 0) {   // stage xA(0) into parity-0
      HU h0, h1u, h2u;
      h0.h = (f16)xl[0]; h1u.h = (f16)xl[1]; h2u.h = (f16)xl[2];
      ast32((unsigned*)AB + (b*1088 >> 1),       (unsigned)h0.u | ((unsigned)h1u.u << 16));
      ast32((unsigned*)AB + ((b*1088 + 2) >> 1), (unsigned)h2u.u);
    }
  }

  // biases into registers
  float bias_g[4] = {0,0,0,0}, bias1a[4] = {0,0,0,0}, bias1b[4] = {0,0,0,0};
  float borow = 0.f;
  float c_st = 0.f, c1a = 0.f, c1b = 0.f;
  if (blk < 64) {
    int pr = tid & 7;
    #pragma unroll
    for (int g = 0; g < 4; ++g) {
      int R = g*512 + blk*8 + pr;
      bias_g[g] = bih2[R] + bhh2[R];
    }
  } else if (blk < 96) {
    int g1i = blk - 64, pr = tid & 7;
    #pragma unroll
    for (int g = 0; g < 4; ++g) {
      int Ra = g*512 + g1i*16 + 2*pr, Rb = Ra + 1;
      bias1a[g] = bih1[Ra] + bhh1[Ra];
      bias1b[g] = bih1[Rb] + bhh1[Rb];
    }
    int r = tid >> 6;
    if (r < 4) { int row = g1i*4 + r; borow = (row < 121) ? bo[row] : 0.f; }
  }

  gbar(bar, 0);

  // ---------------- main recurrence ----------------
  for (int i = 0; i <= 601; ++i) {
    const f16* __restrict__ Acur = AB + (i & 1)*ABE;
    f16* __restrict__ Anxt = AB + ((i & 1)^1)*ABE;
    unsigned* AnxtW = (unsigned*)Anxt;

    // ============ Phase A ============
    if (blk < 64) {
      if (i >= 1 && i <= 600) {
        f16* wf2 = (f16*)dsm;
        float* part2 = (float*)(dsm + 69632);   // [2][64][33]
        const int mt = wv & 3, kh = wv >> 2;
        const int mA = mt*16 + (l & 15);
        const int kb = (l >> 4)*8;
        const f16* Ap = Acur + mA*1088;
        f32x4 acc0 = {0,0,0,0}, acc1 = {0,0,0,0};
        #pragma unroll
        for (int jj = 0; jj < 17; ++jj) {
          int j = kh*17 + jj;
          int k = j*32 + kb;
          AFU af;
          af.q[0] = ald64(Ap + k);
          af.q[1] = ald64(Ap + k + 4);
          f16x8 b0 = *(const f16x8*)&wf2[((0*34 + j)*64 + l)*8];
          f16x8 b1 = *(const f16x8*)&wf2[((1*34 + j)*64 + l)*8];
          acc0 = __builtin_amdgcn_mfma_f32_16x16x32_f16(af.v, b0, acc0, 0, 0, 0);
          acc1 = __builtin_amdgcn_mfma_f32_16x16x32_f16(af.v, b1, acc1, 0, 0, 0);
        }
        #pragma unroll
        for (int r = 0; r < 4; ++r) {
          int m = mt*16 + (l>>4)*4 + r;
          part2[(kh*64 + m)*33 + (l & 15)]      = acc0[r];
          part2[(kh*64 + m)*33 + 16 + (l & 15)] = acc1[r];
        }
        __syncthreads();
        {
          int b_ = tid >> 3, pr = tid & 7;
          const float* p0 = &part2[(0*64 + b_)*33];
          const float* p1 = &part2[(1*64 + b_)*33];
          float gi_ = p0[0*8+pr] + p1[0*8+pr] + bias_g[0];
          float gf_ = p0[1*8+pr] + p1[1*8+pr] + bias_g[1];
          float gg_ = p0[2*8+pr] + p1[2*8+pr] + bias_g[2];
          float go_ = p0[3*8+pr] + p1[3*8+pr] + bias_g[3];
          float ig = sigm(gi_), fg = sigm(gf_), gg2 = tanhf(gg_), og = sigm(go_);
          c_st = fg*c_st + ig*gg2;
          HU hu; hu.h = (f16)(og * tanhf(c_st));
          unsigned myv = hu.u;
          unsigned other = (unsigned)__shfl_xor((int)myv, 1);
          if ((pr & 1) == 0)
            ast32(AnxtW + ((b_*1088 + 576 + blk*8 + pr) >> 1), myv | (other << 16));
        }
      }
    } else if (blk < 96) {
      const int g1i = blk - 64;
      f16* wf1  = (f16*)dsm;
      f16* wofr = (f16*)(dsm + 73728);
      float* part1 = (float*)(dsm + 90112);    // [2][64][65]
      float* partp = (float*)(dsm + 123392);   // [2][64][17]
      bool do_g1 = (i <= 599), do_pr = (i >= 2);
      const int mt = wv & 3, kh = wv >> 2;
      const int mA = mt*16 + (l & 15);
      const int kb = (l >> 4)*8;
      if (do_g1) {
        const f16* Ap = Acur + mA*1088;
        f32x4 acc[4];
        #pragma unroll
        for (int nt = 0; nt < 4; ++nt) acc[nt] = (f32x4){0,0,0,0};
        #pragma unroll
        for (int jj = 0; jj < 9; ++jj) {
          int j = kh*9 + jj;
          int k = j*32 + kb;
          AFU af;
          af.q[0] = ald64(Ap + k);
          af.q[1] = ald64(Ap + k + 4);
          #pragma unroll
          for (int nt = 0; nt < 4; ++nt) {
            f16x8 bf = *(const f16x8*)&wf1[((nt*18 + j)*64 + l)*8];
            acc[nt] = __builtin_amdgcn_mfma_f32_16x16x32_f16(af.v, bf, acc[nt], 0, 0, 0);
          }
        }
        #pragma unroll
        for (int nt = 0; nt < 4; ++nt)
          #pragma unroll
          for (int r = 0; r < 4; ++r) {
            int m = mt*16 + (l>>4)*4 + r;
            part1[(kh*64 + m)*65 + nt*16 + (l & 15)] = acc[nt][r];
          }
      }
      if (do_pr) {
        const f16* Ap = Acur + mA*1088 + 576;
        f32x4 accp = {0,0,0,0};
        #pragma unroll
        for (int jj = 0; jj < 8; ++jj) {
          int j = kh*8 + jj;
          int k = j*32 + kb;
          AFU af;
          af.q[0] = ald64(Ap + k);
          af.q[1] = ald64(Ap + k + 4);
          f16x8 bf = *(const f16x8*)&wofr[(j*64 + l)*8];
          accp = __builtin_amdgcn_mfma_f32_16x16x32_f16(af.v, bf, accp, 0, 0, 0);
        }
        #pragma unroll
        for (int r = 0; r < 4; ++r) {
          int m = mt*16 + (l>>4)*4 + r;
          partp[(kh*64 + m)*17 + (l & 15)] = accp[r];
        }
      }
      if (do_g1 || do_pr) __syncthreads();
      if (do_g1) {
        int b_ = tid >> 3, pr = tid & 7;
        const float* p0 = &part1[(0*64 + b_)*65];
        const float* p1 = &part1[(1*64 + b_)*65];
        // dim A = 2*pr
        float giA = p0[0*16+2*pr] + p1[0*16+2*pr] + bias1a[0];
        float gfA = p0[1*16+2*pr] + p1[1*16+2*pr] + bias1a[1];
        float ggA = p0[2*16+2*pr] + p1[2*16+2*pr] + bias1a[2];
        float goA = p0[3*16+2*pr] + p1[3*16+2*pr] + bias1a[3];
        c1a = sigm(gfA)*c1a + sigm(giA)*tanhf(ggA);
        float hA = sigm(goA) * tanhf(c1a);
        // dim B = 2*pr+1
        float giB = p0[0*16+2*pr+1] + p1[0*16+2*pr+1] + bias1b[0];
        float gfB = p0[1*16+2*pr+1] + p1[1*16+2*pr+1] + bias1b[1];
        float ggB = p0[2*16+2*pr+1] + p1[2*16+2*pr+1] + bias1b[2];
        float goB = p0[3*16+2*pr+1] + p1[3*16+2*pr+1] + bias1b[3];
        c1b = sigm(gfB)*c1b + sigm(giB)*tanhf(ggB);
        float hB = sigm(goB) * tanhf(c1b);
        HU ua, ub; ua.h = (f16)hA; ub.h = (f16)hB;
        ast32(AnxtW + ((b_*1088 + 64 + g1i*16 + 2*pr) >> 1),
              (unsigned)ua.u | ((unsigned)ub.u << 16));
      }
      if (do_pr && tid < 256) {
        int b_ = tid & 63, r = tid >> 6;
        int row = g1i*4 + r;
        if (row < 121) {
          float v = partp[(0*64 + b_)*17 + r] + partp[(1*64 + b_)*17 + r] + borow;
          unsigned uu; __builtin_memcpy(&uu, &v, 4);
          ast32((unsigned*)outg + b_*128 + row, uu);
        }
      }
    }
    gbar(bar, 1 + 2*i);

    // ============ Phase B ============
    if (blk >= 96) {
      const int b = blk - 96;
      f16*   wk   = (f16*)dsm;
      float* cv   = (float*)(dsm + 31200);
      float* xl   = (float*)(dsm + 45024);
      float* yl   = (float*)(dsm + 52224);
      f16*   h1h  = (f16*)(dsm + 59424);
      float* so   = (float*)(dsm + 60448);
      float* skg  = (float*)(dsm + 60944);
      float* sal  = (float*)(dsm + 61072);
      float* sbe  = (float*)(dsm + 61112);
      float* kap  = (float*)(dsm + 61152);
      float* sphi = (float*)(dsm + 61192);
      float* wtmp = (float*)(dsm + 61448);
      if (i <= 599) {
        if (tid < 64)
          ((unsigned long long*)h1h)[tid] = ald64(Anxt + b*1088 + 64 + tid*4);
        __syncthreads();
        {
          int j = tid >> 4, ksv = tid & 15;
          float a = 0.f;
          if (j < 30) {
            const f16* wr = &wk[j*520 + ksv*32];
            const f16* hr = &h1h[ksv*32];
            #pragma unroll
            for (int c = 0; c < 4; ++c) {
              f16x8 q = *(const f16x8*)(wr + c*8);
              f16x8 h = *(const f16x8*)(hr + c*8);
              #pragma unroll
              for (int e = 0; e < 8; ++e) a += (float)q[e] * (float)h[e];
            }
          }
          a += __shfl_xor(a, 1); a += __shfl_xor(a, 2);
          a += __shfl_xor(a, 4); a += __shfl_xor(a, 8);
          if (j < 30 && ksv == 0) skg[j] = a + bk[j];
        }
        __syncthreads();
        if (tid < 10) {
          sal[tid] = expf(skg[tid]);
          sbe[tid] = expf(skg[10+tid]);
          kap[tid] += expf(skg[20+tid]);
        }
        __syncthreads();
        if (tid < 64) {
          float u = (float)tid, ph = 0.f;
          #pragma unroll
          for (int k2 = 0; k2 < 10; ++k2) {
            float d = kap[k2] - u;
            ph += sal[k2]*expf(-sbe[k2]*d*d);
          }
          sphi[tid] = ph;
        }
        __syncthreads();
        if (tid < 54) {
          float wvv = 0.f;
          #pragma unroll 8
          for (int u = 0; u < 64; ++u) wvv += sphi[u]*cv[u*54 + tid];
          wtmp[tid] = wvv;
        }
        __syncthreads();
        if (tid < 27) {
          HU a, bu; a.h = (f16)wtmp[2*tid]; bu.h = (f16)wtmp[2*tid+1];
          ast32(AnxtW + ((b*1088 + 4 + 2*tid) >> 1), (unsigned)a.u | ((unsigned)bu.u << 16));
        } else if (tid == 27) {
          HU a, bu; a.h = (f16)xl[i*3+0]; bu.h = (f16)xl[i*3+1];
          ast32(AnxtW + ((b*1088 + 58) >> 1), (unsigned)a.u | ((unsigned)bu.u << 16));
        } else if (tid == 28) {
          HU a; a.h = (f16)xl[i*3+2];
          ast32(AnxtW + ((b*1088 + 60) >> 1), (unsigned)a.u);
        } else if (tid == 29 && i <= 598) {
          HU a, bu; a.h = (f16)xl[(i+1)*3+0]; bu.h = (f16)xl[(i+1)*3+1];
          ast32(AnxtW + ((b*1088) >> 1), (unsigned)a.u | ((unsigned)bu.u << 16));
        } else if (tid == 30 && i <= 598) {
          HU a; a.h = (f16)xl[(i+1)*3+2];
          ast32(AnxtW + ((b*1088 + 2) >> 1), (unsigned)a.u);
        }
      }
      if (i >= 2) {
        if (tid < 121) {
          unsigned uu = ald32((unsigned*)outg + b*128 + tid);
          float v; __builtin_memcpy(&v, &uu, 4);
          so[tid] = v;
        }
        __syncthreads();
        if (tid < 32) {
          float v = mix_loss(so, yl, i-2, tid);
          if (tid == 0) lreg += v;
        }
      }
    }
    gbar(bar, 2 + 2*i);
  }

  if (blk >= 96 && tid == 0) {
    unsigned uu; __builtin_memcpy(&uu, &lreg, 4);
    ast32((unsigned*)lossg + (blk - 96), uu);
  }
  gbar(bar, 1205);
  if (blk == 96 && tid < 64) {
    unsigned uu = ald32((unsigned*)lossg + tid);
    float v; __builtin_memcpy(&v, &uu, 4);
    #pragma unroll
    for (int d = 32; d >= 1; d >>= 1) v += __shfl_xor(v, d);
    if (tid == 0) out[0] = v / 38400.f;
  }
}

extern "C" void kernel_launch(void* const* d_in, const int* in_sizes, int n_in,
                              void* d_out, int out_size, void* d_ws, size_t ws_size,
                              hipStream_t stream)
{
  (void)in_sizes; (void)n_in; (void)out_size; (void)ws_size;
  const float* x    = (const float*)d_in[0];
  const float* y    = (const float*)d_in[1];
  const float* cvec = (const float*)d_in[2];
  const float* Wih1 = (const float*)d_in[3];
  const float* Whh1 = (const float*)d_in[4];
  const float* bih1 = (const float*)d_in[5];
  const float* bhh1 = (const float*)d_in[6];
  const float* Wih2 = (const float*)d_in[7];
  const float* Whh2 = (const float*)d_in[8];
  const float* bih2 = (const float*)d_in[9];
  const float* bhh2 = (const float*)d_in[10];
  const float* Wk   = (const float*)d_in[11];
  const float* bk   = (const float*)d_in[12];
  const float* Wo   = (const float*)d_in[13];
  const float* bo   = (const float*)d_in[14];
  float* out = (float*)d_out;
  float* wsf = (float*)d_ws;

  hipFuncSetAttribute((const void*)kmain, hipFuncAttributeMaxDynamicSharedMemorySize, DYN_LDS);

  k_init<<<256, 256, 0, stream>>>(wsf);

  void* args[] = {
    (void*)&x, (void*)&y, (void*)&cvec,
    (void*)&Wih1, (void*)&Whh1, (void*)&bih1, (void*)&bhh1,
    (void*)&Wih2, (void*)&Whh2, (void*)&bih2, (void*)&bhh2,
    (void*)&Wk, (void*)&bk, (void*)&Wo, (void*)&bo,
    (void*)&out, (void*)&wsf
  };
  hipLaunchCooperativeKernel((void*)kmain, dim3(NBLK), dim3(NT), args, DYN_LDS, stream);
}